// Round 2
// baseline (1889.048 us; speedup 1.0000x reference)
//
#include <hip/hip_runtime.h>
#include <hip/hip_fp16.h>

#define N_ROWS 65536
#define D_COLS 1024
#define M_ROWS 32768

using u32 = unsigned int;

// ---- ws[0] = 0 (abs-max accumulator) ----
__global__ void init_ws_k(u32* ws) {
    if (threadIdx.x == 0 && blockIdx.x == 0) ws[0] = 0u;
}

// ---- out[i] = (float)var[i] * var_scale; var arrives as int32 (sign-extended int8) ----
__global__ __launch_bounds__(256) void dequant_k(const int4* __restrict__ var4,
                                                 const float* __restrict__ var_scale,
                                                 float4* __restrict__ outf4, int n4) {
    const float s = var_scale[0];
    int i = blockIdx.x * 256 + threadIdx.x;
    const int stride = gridDim.x * 256;
    for (; i < n4; i += stride) {
        int4 v = var4[i];
        float4 o;
        o.x = (float)v.x * s;
        o.y = (float)v.y * s;
        o.z = (float)v.z * s;
        o.w = (float)v.w * s;
        outf4[i] = o;
    }
}

// ---- out[idx[i,j], j] += f32(fp16(upd[i,j]) * fp16(scale[j])); upd/scale arrive as f32 ----
__global__ __launch_bounds__(256) void scatter_k(const int4* __restrict__ idx4,
                                                 const float4* __restrict__ upd4,
                                                 const float4* __restrict__ scl4,
                                                 float* __restrict__ outf, int t4) {
    int t = blockIdx.x * 256 + threadIdx.x;
    const int stride = gridDim.x * 256;
    for (; t < t4; t += stride) {
        int4 idx = idx4[t];
        float4 u = upd4[t];
        float4 sc = scl4[t & (D_COLS / 4 - 1)];
        // reference computes updates*smooth_scales in fp16, then promotes to f32
        float f0 = __half2float(__hmul(__float2half(u.x), __float2half(sc.x)));
        float f1 = __half2float(__hmul(__float2half(u.y), __float2half(sc.y)));
        float f2 = __half2float(__hmul(__float2half(u.z), __float2half(sc.z)));
        float f3 = __half2float(__hmul(__float2half(u.w), __float2half(sc.w)));
        int j0 = (t << 2) & (D_COLS - 1);
        atomicAdd(outf + (size_t)idx.x * D_COLS + j0 + 0, f0);
        atomicAdd(outf + (size_t)idx.y * D_COLS + j0 + 1, f1);
        atomicAdd(outf + (size_t)idx.z * D_COLS + j0 + 2, f2);
        atomicAdd(outf + (size_t)idx.w * D_COLS + j0 + 3, f3);
    }
}

// ---- global abs-max of out -> ws[0] (uint-bit compare; values >= 0) ----
__global__ __launch_bounds__(256) void absmax_k(const float4* __restrict__ outf4,
                                                u32* __restrict__ ws, int n4) {
    float m = 0.f;
    int i = blockIdx.x * 256 + threadIdx.x;
    const int stride = gridDim.x * 256;
    for (; i < n4; i += stride) {
        float4 v = outf4[i];
        m = fmaxf(m, fmaxf(fmaxf(fabsf(v.x), fabsf(v.y)),
                           fmaxf(fabsf(v.z), fabsf(v.w))));
    }
    for (int off = 32; off; off >>= 1) m = fmaxf(m, __shfl_xor(m, off));
    __shared__ float sm[4];
    int lane = threadIdx.x & 63, w = threadIdx.x >> 6;
    if (lane == 0) sm[w] = m;
    __syncthreads();
    if (threadIdx.x == 0) {
        m = fmaxf(fmaxf(sm[0], sm[1]), fmaxf(sm[2], sm[3]));
        atomicMax(ws, __float_as_uint(m));
    }
}

// ---- y = clip(rint(out * 127/max), -128, 127) stored as f32; write scale ----
__global__ __launch_bounds__(256) void quant_k(const float4* __restrict__ outf4,
                                               float4* __restrict__ y4,
                                               const u32* __restrict__ ws,
                                               float* __restrict__ scale_out, int n4) {
    const float mx = __uint_as_float(ws[0]);
    const float inv = 127.0f / mx;
    int gid = blockIdx.x * 256 + threadIdx.x;
    if (gid == 0) scale_out[0] = mx / 127.0f;
    const int stride = gridDim.x * 256;
    for (int i = gid; i < n4; i += stride) {
        float4 v = outf4[i];
        float4 o;
        o.x = fminf(fmaxf(rintf(v.x * inv), -128.f), 127.f);
        o.y = fminf(fmaxf(rintf(v.y * inv), -128.f), 127.f);
        o.z = fminf(fmaxf(rintf(v.z * inv), -128.f), 127.f);
        o.w = fminf(fmaxf(rintf(v.w * inv), -128.f), 127.f);
        y4[i] = o;
    }
}

extern "C" void kernel_launch(void* const* d_in, const int* in_sizes, int n_in,
                              void* d_out, int out_size, void* d_ws, size_t ws_size,
                              hipStream_t stream) {
    const int4*   var4      = (const int4*)d_in[0];      // int8 [N,D] arrives as int32
    const float*  var_scale = (const float*)d_in[1];     // f32 [1]
    const int4*   idx4      = (const int4*)d_in[2];      // int32 [M,D]
    const float4* upd4      = (const float4*)d_in[3];    // fp16 [M,D] arrives as f32
    const float4* scl4      = (const float4*)d_in[4];    // fp16 [D] arrives as f32

    float* y    = (float*)d_out;                         // y as f32 [N*D]
    float* outf = y + (size_t)N_ROWS * D_COLS;           // out f32 [N*D]
    float* scale_out = y + 2 * (size_t)N_ROWS * D_COLS;  // new_scale [1]
    u32* ws = (u32*)d_ws;

    const int n4 = N_ROWS * D_COLS / 4;  // 16,777,216 groups of 4
    const int t4 = M_ROWS * D_COLS / 4;  //  8,388,608 groups of 4

    init_ws_k<<<1, 64, 0, stream>>>(ws);
    dequant_k<<<2048, 256, 0, stream>>>(var4, var_scale, (float4*)outf, n4);
    scatter_k<<<2048, 256, 0, stream>>>(idx4, upd4, scl4, outf, t4);
    absmax_k<<<2048, 256, 0, stream>>>((const float4*)outf, ws, n4);
    quant_k<<<2048, 256, 0, stream>>>((const float4*)outf, (float4*)y, ws, scale_out, n4);
}

// Round 3
// 1219.612 us; speedup vs baseline: 1.5489x; 1.5489x over previous
//
#include <hip/hip_runtime.h>
#include <hip/hip_fp16.h>

#define N_ROWS 65536
#define D_COLS 1024
#define M_ROWS 32768
#define QROWS  16384   // rows per scatter workgroup (64KB f32 LDS)

using u32 = unsigned int;
using u16 = unsigned short;

// ---- ws[0] = 0 (abs-max accumulator) ----
__global__ void init_ws_k(u32* ws) {
    if (threadIdx.x == 0 && blockIdx.x == 0) ws[0] = 0u;
}

// ---- transpose idx[M,D]->idxT[D,M] (u16) and upd[M,D]*scale[j] -> updT[D,M] (fp16) ----
__global__ __launch_bounds__(256) void t_idx_upd_k(const int* __restrict__ idx,
                                                   const float* __restrict__ upd,
                                                   const float* __restrict__ scl,
                                                   u16* __restrict__ idxT,
                                                   __half* __restrict__ updT) {
    __shared__ u16   sidx[32][33];
    __shared__ __half supd[32][33];
    const int jb = (blockIdx.x & 31) * 32;        // 1024/32 = 32 j-tiles
    const int ib = (blockIdx.x >> 5) * 32;        // 32768/32 = 1024 i-tiles
    const int tx = threadIdx.x & 31, ty = threadIdx.x >> 5;   // 8 rows of 32
    const __half hs = __float2half(scl[jb + tx]); // scale of column jb+tx (exact fp16)
    #pragma unroll
    for (int k = 0; k < 4; ++k) {
        const size_t p = (size_t)(ib + ty + k * 8) * D_COLS + (jb + tx);
        sidx[ty + k * 8][tx] = (u16)idx[p];
        supd[ty + k * 8][tx] = __hmul(__float2half(upd[p]), hs); // fp16 mult = reference
    }
    __syncthreads();
    #pragma unroll
    for (int k = 0; k < 4; ++k) {
        const int jj = ty + k * 8;   // local col
        const size_t q = (size_t)(jb + jj) * M_ROWS + (ib + tx);
        idxT[q] = sidx[tx][jj];
        updT[q] = supd[tx][jj];
    }
}

// ---- transpose var[N,D] (int32-transported int8) -> varT[D,N] (int8) ----
__global__ __launch_bounds__(256) void t_var_k(const int* __restrict__ var,
                                               signed char* __restrict__ varT) {
    __shared__ signed char sv[32][33];
    const int jb = (blockIdx.x & 31) * 32;
    const int ib = (blockIdx.x >> 5) * 32;        // 65536/32 = 2048 i-tiles
    const int tx = threadIdx.x & 31, ty = threadIdx.x >> 5;
    #pragma unroll
    for (int k = 0; k < 4; ++k)
        sv[ty + k * 8][tx] = (signed char)var[(size_t)(ib + ty + k * 8) * D_COLS + (jb + tx)];
    __syncthreads();
    #pragma unroll
    for (int k = 0; k < 4; ++k)
        varT[(size_t)(jb + ty + k * 8) * N_ROWS + (ib + tx)] = sv[tx][ty + k * 8];
}

// ---- per (column, row-quarter): dequant base into LDS, accumulate updates via
//      LDS atomics, dense write-back of final values (no global atomics),
//      fused global abs-max. ----
__global__ __launch_bounds__(512) void scatter_col_k(const signed char* __restrict__ varT,
                                                     const u16* __restrict__ idxT,
                                                     const __half* __restrict__ updT,
                                                     const float* __restrict__ var_scale,
                                                     float* __restrict__ outf,
                                                     u32* __restrict__ ws) {
    __shared__ float acc[QROWS];                  // 64 KB
    // bijective XCD-chunk swizzle (4096 % 8 == 0): XCD k owns 128 consecutive columns
    int bid = (blockIdx.x & 7) * 512 + (blockIdx.x >> 3);
    const int j = bid >> 2;                       // column 0..1023
    const int h = bid & 3;                        // row quarter 0..3
    const int rbase = h * QROWS;
    const int tid = threadIdx.x;
    const float s = var_scale[0];

    // 1) base: dequant 16384 int8s (coalesced int loads, float4 LDS writes)
    const int* v1 = (const int*)(varT + (size_t)j * N_ROWS + rbase);  // 4096 ints
    float4* acc4 = (float4*)acc;
    for (int t = tid; t < 4096; t += 512) {
        const int p = v1[t];
        float4 f;
        f.x = (float)((signed char)(p      )) * s;
        f.y = (float)((signed char)(p >> 8 )) * s;
        f.z = (float)((signed char)(p >> 16)) * s;
        f.w = (float)((signed char)(p >> 24)) * s;
        acc4[t] = f;
    }
    __syncthreads();

    // 2) scan all M updates of column j; keep rows in our quarter (LDS atomics)
    const uint* ip = (const uint*)(idxT + (size_t)j * M_ROWS);  // 2 u16 / uint
    const uint* up = (const uint*)(updT + (size_t)j * M_ROWS);  // 2 fp16 / uint
    for (int t = tid; t < M_ROWS / 2; t += 512) {
        const uint iv = ip[t];
        const uint uv = up[t];
        const int r0 = iv & 0xffff, r1 = iv >> 16;
        const __half2 h2 = *reinterpret_cast<const __half2*>(&uv);
        if ((r0 >> 14) == h) atomicAdd(&acc[r0 & (QROWS - 1)], __half2float(__low2half(h2)));
        if ((r1 >> 14) == h) atomicAdd(&acc[r1 & (QROWS - 1)], __half2float(__high2half(h2)));
    }
    __syncthreads();

    // 3) dense write-back of final values + fused abs-max
    float m = 0.f;
    for (int t = tid; t < QROWS; t += 512) {
        const float v = acc[t];
        outf[(size_t)(rbase + t) * D_COLS + j] = v;
        m = fmaxf(m, fabsf(v));
    }
    for (int off = 32; off; off >>= 1) m = fmaxf(m, __shfl_xor(m, off));
    if ((tid & 63) == 0) atomicMax(ws, __float_as_uint(m));   // 8 atomics/WG
}

// ---- y = clip(rint(out * 127/max), -128, 127) stored as f32; write scale ----
__global__ __launch_bounds__(256) void quant_k(const float4* __restrict__ outf4,
                                               float4* __restrict__ y4,
                                               const u32* __restrict__ ws,
                                               float* __restrict__ scale_out, int n4) {
    const float mx = __uint_as_float(ws[0]);
    const float inv = 127.0f / mx;
    int gid = blockIdx.x * 256 + threadIdx.x;
    if (gid == 0) scale_out[0] = mx / 127.0f;
    const int stride = gridDim.x * 256;
    for (int i = gid; i < n4; i += stride) {
        float4 v = outf4[i];
        float4 o;
        o.x = fminf(fmaxf(rintf(v.x * inv), -128.f), 127.f);
        o.y = fminf(fmaxf(rintf(v.y * inv), -128.f), 127.f);
        o.z = fminf(fmaxf(rintf(v.z * inv), -128.f), 127.f);
        o.w = fminf(fmaxf(rintf(v.w * inv), -128.f), 127.f);
        y4[i] = o;
    }
}

extern "C" void kernel_launch(void* const* d_in, const int* in_sizes, int n_in,
                              void* d_out, int out_size, void* d_ws, size_t ws_size,
                              hipStream_t stream) {
    const int*   var       = (const int*)d_in[0];     // int8 transported as int32
    const float* var_scale = (const float*)d_in[1];
    const int*   idx       = (const int*)d_in[2];
    const float* upd       = (const float*)d_in[3];   // fp16 transported as f32
    const float* scl       = (const float*)d_in[4];   // fp16 transported as f32

    float* y    = (float*)d_out;                      // y (f32) [N*D]
    float* outf = y + (size_t)N_ROWS * D_COLS;        // out (f32) [N*D]
    float* scale_out = y + 2 * (size_t)N_ROWS * D_COLS;

    // scratch packed into the (not-yet-written) y region: 201.3 MB of 268.4 MB
    char* scratch = (char*)y;
    u16*         idxT = (u16*)scratch;                               // 67.1 MB
    __half*      updT = (__half*)(scratch + (size_t)67108864);       // 67.1 MB
    signed char* varT = (signed char*)(scratch + (size_t)134217728); // 67.1 MB
    u32* ws = (u32*)d_ws;

    const int n4 = N_ROWS * D_COLS / 4;

    init_ws_k<<<1, 64, 0, stream>>>(ws);
    t_idx_upd_k<<<32768, 256, 0, stream>>>(idx, upd, scl, idxT, updT);
    t_var_k<<<65536, 256, 0, stream>>>(var, varT);
    scatter_col_k<<<4096, 512, 0, stream>>>(varT, idxT, updT, var_scale, outf, ws);
    quant_k<<<2048, 256, 0, stream>>>((const float4*)outf, (float4*)y, ws, scale_out, n4);
}

// Round 4
// 609.443 us; speedup vs baseline: 3.0996x; 2.0012x over previous
//
#include <hip/hip_runtime.h>
#include <hip/hip_fp16.h>

#define N_ROWS 65536
#define D_COLS 1024
#define M_ROWS 32768
#define HROWS  32768   // rows per scatter workgroup (128KB f32 LDS)

using u32 = unsigned int;
using u16 = unsigned short;

// ---- ws[0] = 0 (abs-max accumulator) ----
__global__ void init_ws_k(u32* ws) {
    if (threadIdx.x == 0 && blockIdx.x == 0) ws[0] = 0u;
}

// ---- transpose idx[M,D]->idxT[D,M] (u16) and upd[M,D]*scale[j] -> updT[D,M] (fp16) ----
__global__ __launch_bounds__(256) void t_idx_upd_k(const int* __restrict__ idx,
                                                   const float* __restrict__ upd,
                                                   const float* __restrict__ scl,
                                                   u16* __restrict__ idxT,
                                                   __half* __restrict__ updT) {
    __shared__ u16   sidx[32][33];
    __shared__ __half supd[32][33];
    const int jb = (blockIdx.x & 31) * 32;        // 1024/32 = 32 j-tiles
    const int ib = (blockIdx.x >> 5) * 32;        // 32768/32 = 1024 i-tiles
    const int tx = threadIdx.x & 31, ty = threadIdx.x >> 5;   // 8 rows of 32
    const __half hs = __float2half(scl[jb + tx]); // scale of column jb+tx (exact fp16)
    #pragma unroll
    for (int k = 0; k < 4; ++k) {
        const size_t p = (size_t)(ib + ty + k * 8) * D_COLS + (jb + tx);
        sidx[ty + k * 8][tx] = (u16)idx[p];
        supd[ty + k * 8][tx] = __hmul(__float2half(upd[p]), hs); // fp16 mult = reference
    }
    __syncthreads();
    #pragma unroll
    for (int k = 0; k < 4; ++k) {
        const int jj = ty + k * 8;   // local col
        const size_t q = (size_t)(jb + jj) * M_ROWS + (ib + tx);
        idxT[q] = sidx[tx][jj];
        updT[q] = supd[tx][jj];
    }
}

// ---- per (column j, half h): zero 128KB LDS f32 acc, accumulate this column's
//      updates via LDS atomics, dense fp16 write of update-sums to sumT[D][N]. ----
__global__ __launch_bounds__(512) void scatter_half_k(const u16* __restrict__ idxT,
                                                      const __half* __restrict__ updT,
                                                      __half* __restrict__ sumT) {
    __shared__ float acc[HROWS];                  // 128 KB
    // bijective XCD-chunk swizzle (2048 % 8 == 0): both halves of a column on one XCD
    const int bid = (blockIdx.x & 7) * 256 + (blockIdx.x >> 3);
    const int j = bid >> 1;                       // column 0..1023
    const int h = bid & 1;                        // row half
    const int rbase = h * HROWS;
    const int tid = threadIdx.x;

    float4* acc4 = (float4*)acc;
    for (int t = tid; t < HROWS / 4; t += 512) acc4[t] = float4{0.f, 0.f, 0.f, 0.f};
    __syncthreads();

    const u32* ip = (const u32*)(idxT + (size_t)j * M_ROWS);  // 2 u16 / u32
    const u32* up = (const u32*)(updT + (size_t)j * M_ROWS);  // 2 fp16 / u32
    for (int t = tid; t < M_ROWS / 2; t += 512) {
        const u32 iv = ip[t];
        const u32 uv = up[t];
        const int r0 = iv & 0xffff, r1 = iv >> 16;
        const __half2 h2 = *reinterpret_cast<const __half2*>(&uv);
        if ((r0 >> 15) == h) atomicAdd(&acc[r0 & (HROWS - 1)], __half2float(__low2half(h2)));
        if ((r1 >> 15) == h) atomicAdd(&acc[r1 & (HROWS - 1)], __half2float(__high2half(h2)));
    }
    __syncthreads();

    __half2* dst = (__half2*)(sumT + (size_t)j * N_ROWS + rbase);
    for (int t = tid; t < HROWS / 2; t += 512)
        dst[t] = __floats2half2_rn(acc[2 * t], acc[2 * t + 1]);
}

// ---- 64x64 tiles: out = var*s + sumT^T, row-major coalesced write, fused abs-max ----
__global__ __launch_bounds__(256) void finalize_k(const int* __restrict__ var,
                                                  const __half* __restrict__ sumT,
                                                  const float* __restrict__ var_scale,
                                                  float* __restrict__ outf,
                                                  u32* __restrict__ ws) {
    __shared__ float sm[64][65];
    __shared__ float wmax[4];
    const int r0 = (int)(blockIdx.x >> 4) * 64;   // 1024 row-tiles
    const int j0 = (int)(blockIdx.x & 15) * 64;   // 16 col-tiles
    const int tid = threadIdx.x;
    const float s = var_scale[0];

    // stage sumT tile (64 cols x 64 rows, contiguous 128B per col) into row-major LDS
    #pragma unroll
    for (int k = 0; k < 16; ++k) {
        const int l = k * 256 + tid;
        const int jj = l >> 6, rr = l & 63;
        sm[rr][jj] = __half2float(sumT[(size_t)(j0 + jj) * N_ROWS + (r0 + rr)]);
    }
    __syncthreads();

    float m = 0.f;
    #pragma unroll
    for (int k = 0; k < 4; ++k) {
        const int l = k * 256 + tid;              // 0..1023 int4 units
        const int rr = l >> 4, c4 = l & 15;
        const int4 v = ((const int4*)(var + (size_t)(r0 + rr) * D_COLS + j0))[c4];
        float4 o;
        o.x = (float)v.x * s + sm[rr][c4 * 4 + 0];
        o.y = (float)v.y * s + sm[rr][c4 * 4 + 1];
        o.z = (float)v.z * s + sm[rr][c4 * 4 + 2];
        o.w = (float)v.w * s + sm[rr][c4 * 4 + 3];
        ((float4*)(outf + (size_t)(r0 + rr) * D_COLS + j0))[c4] = o;
        m = fmaxf(m, fmaxf(fmaxf(fabsf(o.x), fabsf(o.y)),
                           fmaxf(fabsf(o.z), fabsf(o.w))));
    }
    for (int off = 32; off; off >>= 1) m = fmaxf(m, __shfl_xor(m, off));
    if ((tid & 63) == 0) wmax[tid >> 6] = m;
    __syncthreads();
    if (tid == 0) {
        m = fmaxf(fmaxf(wmax[0], wmax[1]), fmaxf(wmax[2], wmax[3]));
        atomicMax(ws, __float_as_uint(m));
    }
}

// ---- y = clip(rint(out * 127/max), -128, 127) stored as f32; write scale ----
__global__ __launch_bounds__(256) void quant_k(const float4* __restrict__ outf4,
                                               float4* __restrict__ y4,
                                               const u32* __restrict__ ws,
                                               float* __restrict__ scale_out, int n4) {
    const float mx = __uint_as_float(ws[0]);
    const float inv = 127.0f / mx;
    int gid = blockIdx.x * 256 + threadIdx.x;
    if (gid == 0) scale_out[0] = mx / 127.0f;
    const int stride = gridDim.x * 256;
    for (int i = gid; i < n4; i += stride) {
        float4 v = outf4[i];
        float4 o;
        o.x = fminf(fmaxf(rintf(v.x * inv), -128.f), 127.f);
        o.y = fminf(fmaxf(rintf(v.y * inv), -128.f), 127.f);
        o.z = fminf(fmaxf(rintf(v.z * inv), -128.f), 127.f);
        o.w = fminf(fmaxf(rintf(v.w * inv), -128.f), 127.f);
        y4[i] = o;
    }
}

extern "C" void kernel_launch(void* const* d_in, const int* in_sizes, int n_in,
                              void* d_out, int out_size, void* d_ws, size_t ws_size,
                              hipStream_t stream) {
    const int*   var       = (const int*)d_in[0];     // int8 transported as int32
    const float* var_scale = (const float*)d_in[1];
    const int*   idx       = (const int*)d_in[2];
    const float* upd       = (const float*)d_in[3];   // fp16 transported as f32
    const float* scl       = (const float*)d_in[4];   // fp16 transported as f32

    float* y    = (float*)d_out;                      // y (f32) [N*D]
    float* outf = y + (size_t)N_ROWS * D_COLS;        // out (f32) [N*D]
    float* scale_out = y + 2 * (size_t)N_ROWS * D_COLS;

    // scratch packed into the (not-yet-written) y region: exactly 268.4 MB
    char* scratch = (char*)y;
    u16*    idxT = (u16*)scratch;                               // 67.1 MB
    __half* updT = (__half*)(scratch + (size_t)67108864);       // 67.1 MB
    __half* sumT = (__half*)(scratch + (size_t)134217728);      // 134.2 MB
    u32* ws = (u32*)d_ws;

    const int n4 = N_ROWS * D_COLS / 4;

    init_ws_k<<<1, 64, 0, stream>>>(ws);
    t_idx_upd_k<<<32768, 256, 0, stream>>>(idx, upd, scl, idxT, updT);
    scatter_half_k<<<2048, 512, 0, stream>>>(idxT, updT, sumT);
    finalize_k<<<16384, 256, 0, stream>>>(var, sumT, var_scale, outf, ws);
    quant_k<<<2048, 256, 0, stream>>>((const float4*)outf, (float4*)y, ws, scale_out, n4);
}

// Round 7
// 597.358 us; speedup vs baseline: 3.1623x; 1.0202x over previous
//
#include <hip/hip_runtime.h>
#include <hip/hip_fp16.h>

#define N_ROWS 65536
#define D_COLS 1024
#define M_ROWS 32768
#define HROWS  32768   // rows per scatter workgroup (128KB f32 LDS)

using u32 = unsigned int;
using u16 = unsigned short;
typedef float f32x4 __attribute__((ext_vector_type(4)));   // native vec for nontemporal

// ---- ws[0] = 0 (abs-max accumulator) ----
__global__ void init_ws_k(u32* ws) {
    if (threadIdx.x == 0 && blockIdx.x == 0) ws[0] = 0u;
}

// ---- 64x64-tile transpose: idx[M,D]->idxT[D,M] (u16), upd[M,D]*scl[j] -> updT[D,M] (fp16)
//      16B vectorized loads and stores. ----
__global__ __launch_bounds__(256) void t_idx_upd_k(const int* __restrict__ idx,
                                                   const float* __restrict__ upd,
                                                   const float* __restrict__ scl,
                                                   u16* __restrict__ idxT,
                                                   __half* __restrict__ updT) {
    __shared__ u32   sidx[64][65];
    __shared__ float supd[64][65];
    const int j0 = (int)(blockIdx.x & 15) * 64;   // 16 j-tiles
    const int i0 = (int)(blockIdx.x >> 4) * 64;   // 512 i-tiles
    const int t = threadIdx.x;

    // load: thread (rr = t>>2, c4 = t&3) loads 4 int4/float4 across the 64 cols
    {
        const int rr = t >> 2, c4 = t & 3;
        const int*   ip = idx + (size_t)(i0 + rr) * D_COLS + j0;
        const float* up = upd + (size_t)(i0 + rr) * D_COLS + j0;
        #pragma unroll
        for (int cq = 0; cq < 4; ++cq) {
            const int jc = cq * 16 + c4 * 4;
            const int4   iv = *(const int4*)(ip + jc);
            const float4 uv = *(const float4*)(up + jc);
            sidx[rr][jc] = (u32)iv.x; sidx[rr][jc+1] = (u32)iv.y;
            sidx[rr][jc+2] = (u32)iv.z; sidx[rr][jc+3] = (u32)iv.w;
            supd[rr][jc] = uv.x; supd[rr][jc+1] = uv.y;
            supd[rr][jc+2] = uv.z; supd[rr][jc+3] = uv.w;
        }
    }
    __syncthreads();

    // store: thread (jj = t>>2, seg = t&3) packs 16 rows of column jj -> 2 uint4 per array
    {
        const int jj = t >> 2, seg = t & 3;
        const __half hs = __float2half(scl[j0 + jj]);   // exact fp16 scale
        u32 wi[8], wh[8];
        #pragma unroll
        for (int p = 0; p < 8; ++p) {
            const int r = seg * 16 + 2 * p;
            const u32 a = sidx[r][jj] & 0xffffu, b = sidx[r + 1][jj] & 0xffffu;
            wi[p] = a | (b << 16);
            const __half2 h2 = __halves2half2(__hmul(__float2half(supd[r][jj]), hs),
                                              __hmul(__float2half(supd[r + 1][jj]), hs));
            wh[p] = *reinterpret_cast<const u32*>(&h2);
        }
        u16* di = idxT + (size_t)(j0 + jj) * M_ROWS + i0 + seg * 16;
        __half* dh = updT + (size_t)(j0 + jj) * M_ROWS + i0 + seg * 16;
        ((uint4*)di)[0] = uint4{wi[0], wi[1], wi[2], wi[3]};
        ((uint4*)di)[1] = uint4{wi[4], wi[5], wi[6], wi[7]};
        ((uint4*)dh)[0] = uint4{wh[0], wh[1], wh[2], wh[3]};
        ((uint4*)dh)[1] = uint4{wh[4], wh[5], wh[6], wh[7]};
    }
}

// ---- per (column j, half h): zero 128KB LDS f32 acc, accumulate this column's
//      updates via LDS atomics (int4-vectorized scan, loads hoisted), dense fp16
//      write of update-sums to sumT[D][N]. ----
__global__ __launch_bounds__(1024) void scatter_half_k(const u16* __restrict__ idxT,
                                                       const __half* __restrict__ updT,
                                                       __half* __restrict__ sumT) {
    __shared__ float acc[HROWS];                  // 128 KB
    // bijective XCD-chunk swizzle (2048 % 8 == 0): both halves of a column on one XCD
    const int bid = (blockIdx.x & 7) * 256 + (blockIdx.x >> 3);
    const int j = bid >> 1;                       // column 0..1023
    const int h = bid & 1;                        // row half
    const int tid = threadIdx.x;

    float4* acc4 = (float4*)acc;
    for (int t = tid; t < HROWS / 4; t += 1024) acc4[t] = float4{0.f, 0.f, 0.f, 0.f};

    // hoist all scan loads (4 int4 pairs = 32 updates/thread) for MLP
    const int4* ip4 = (const int4*)(idxT + (size_t)j * M_ROWS);  // 4096 int4
    const int4* up4 = (const int4*)(updT + (size_t)j * M_ROWS);
    int4 iv[4], uv[4];
    #pragma unroll
    for (int k = 0; k < 4; ++k) {
        iv[k] = ip4[k * 1024 + tid];
        uv[k] = up4[k * 1024 + tid];
    }
    __syncthreads();

    #pragma unroll
    for (int k = 0; k < 4; ++k) {
        const u32 iw[4] = {(u32)iv[k].x, (u32)iv[k].y, (u32)iv[k].z, (u32)iv[k].w};
        const u32 uw[4] = {(u32)uv[k].x, (u32)uv[k].y, (u32)uv[k].z, (u32)uv[k].w};
        #pragma unroll
        for (int e = 0; e < 4; ++e) {
            const int r0 = iw[e] & 0xffff, r1 = iw[e] >> 16;
            const __half2 h2 = *reinterpret_cast<const __half2*>(&uw[e]);
            if ((r0 >> 15) == h) atomicAdd(&acc[r0 & (HROWS - 1)], __half2float(__low2half(h2)));
            if ((r1 >> 15) == h) atomicAdd(&acc[r1 & (HROWS - 1)], __half2float(__high2half(h2)));
        }
    }
    __syncthreads();

    __half2* dst = (__half2*)(sumT + (size_t)j * N_ROWS + h * HROWS);
    for (int t = tid; t < HROWS / 2; t += 1024)
        dst[t] = __floats2half2_rn(acc[2 * t], acc[2 * t + 1]);
}

// ---- 64x64 tiles: out = var*s + sumT^T, row-major coalesced write, fused abs-max ----
__global__ __launch_bounds__(256) void finalize_k(const int* __restrict__ var,
                                                  const __half* __restrict__ sumT,
                                                  const float* __restrict__ var_scale,
                                                  float* __restrict__ outf,
                                                  u32* __restrict__ ws) {
    __shared__ float sm[64][65];
    __shared__ float wmax[4];
    const int r0 = (int)(blockIdx.x >> 4) * 64;   // 1024 row-tiles
    const int j0 = (int)(blockIdx.x & 15) * 64;   // 16 col-tiles
    const int tid = threadIdx.x;
    const float s = var_scale[0];

    // stage sumT tile: thread (jj = tid>>2, seg = tid&3) loads 16 halves (2x16B)
    {
        const int jj = tid >> 2, seg = tid & 3;
        const __half* colp = sumT + (size_t)(j0 + jj) * N_ROWS + r0 + seg * 16;
        #pragma unroll
        for (int q = 0; q < 2; ++q) {
            const uint4 w = ((const uint4*)colp)[q];
            const u32 wv[4] = {w.x, w.y, w.z, w.w};
            #pragma unroll
            for (int i = 0; i < 4; ++i) {
                const __half2 hh = *reinterpret_cast<const __half2*>(&wv[i]);
                const float2 f = __half22float2(hh);
                const int rr = seg * 16 + q * 8 + i * 2;
                sm[rr][jj] = f.x;
                sm[rr + 1][jj] = f.y;
            }
        }
    }
    __syncthreads();

    float m = 0.f;
    #pragma unroll
    for (int k = 0; k < 4; ++k) {
        const int l = k * 256 + tid;              // 0..1023 int4 units
        const int rr = l >> 4, c4 = l & 15;
        const int4 v = ((const int4*)(var + (size_t)(r0 + rr) * D_COLS + j0))[c4];
        float4 o;
        o.x = (float)v.x * s + sm[rr][c4 * 4 + 0];
        o.y = (float)v.y * s + sm[rr][c4 * 4 + 1];
        o.z = (float)v.z * s + sm[rr][c4 * 4 + 2];
        o.w = (float)v.w * s + sm[rr][c4 * 4 + 3];
        ((float4*)(outf + (size_t)(r0 + rr) * D_COLS + j0))[c4] = o;
        m = fmaxf(m, fmaxf(fmaxf(fabsf(o.x), fabsf(o.y)),
                           fmaxf(fabsf(o.z), fabsf(o.w))));
    }
    for (int off = 32; off; off >>= 1) m = fmaxf(m, __shfl_xor(m, off));
    if ((tid & 63) == 0) wmax[tid >> 6] = m;
    __syncthreads();
    if (tid == 0) {
        m = fmaxf(fmaxf(wmax[0], wmax[1]), fmaxf(wmax[2], wmax[3]));
        atomicMax(ws, __float_as_uint(m));
    }
}

// ---- y = clip(rint(out * 127/max), -128, 127) stored as f32; write scale ----
__global__ __launch_bounds__(256) void quant_k(const float4* __restrict__ outf4,
                                               f32x4* __restrict__ y4,
                                               const u32* __restrict__ ws,
                                               float* __restrict__ scale_out, int n4) {
    const float mx = __uint_as_float(ws[0]);
    const float inv = 127.0f / mx;
    int gid = blockIdx.x * 256 + threadIdx.x;
    if (gid == 0) scale_out[0] = mx / 127.0f;
    const int stride = gridDim.x * 256;
    for (int i = gid; i < n4; i += stride) {
        float4 v = outf4[i];
        f32x4 o;
        o.x = fminf(fmaxf(rintf(v.x * inv), -128.f), 127.f);
        o.y = fminf(fmaxf(rintf(v.y * inv), -128.f), 127.f);
        o.z = fminf(fmaxf(rintf(v.z * inv), -128.f), 127.f);
        o.w = fminf(fmaxf(rintf(v.w * inv), -128.f), 127.f);
        __builtin_nontemporal_store(o, &y4[i]);   // y never re-read; keep L3 for out
    }
}

extern "C" void kernel_launch(void* const* d_in, const int* in_sizes, int n_in,
                              void* d_out, int out_size, void* d_ws, size_t ws_size,
                              hipStream_t stream) {
    const int*   var       = (const int*)d_in[0];     // int8 transported as int32
    const float* var_scale = (const float*)d_in[1];
    const int*   idx       = (const int*)d_in[2];
    const float* upd       = (const float*)d_in[3];   // fp16 transported as f32
    const float* scl       = (const float*)d_in[4];   // fp16 transported as f32

    float* y    = (float*)d_out;                      // y (f32) [N*D]
    float* outf = y + (size_t)N_ROWS * D_COLS;        // out (f32) [N*D]
    float* scale_out = y + 2 * (size_t)N_ROWS * D_COLS;

    // scratch packed into the (not-yet-written) y region: exactly 256 MB
    char* scratch = (char*)y;
    u16*    idxT = (u16*)scratch;                               // 64 MB
    __half* updT = (__half*)(scratch + (size_t)67108864);       // 64 MB
    __half* sumT = (__half*)(scratch + (size_t)134217728);      // 128 MB
    u32* ws = (u32*)d_ws;

    const int n4 = N_ROWS * D_COLS / 4;

    init_ws_k<<<1, 64, 0, stream>>>(ws);
    t_idx_upd_k<<<8192, 256, 0, stream>>>(idx, upd, scl, idxT, updT);
    scatter_half_k<<<2048, 1024, 0, stream>>>(idxT, updT, sumT);
    finalize_k<<<16384, 256, 0, stream>>>(var, sumT, var_scale, outf, ws);
    quant_k<<<4096, 256, 0, stream>>>((const float4*)outf, (f32x4*)y, ws, scale_out, n4);
}

// Round 8
// 574.386 us; speedup vs baseline: 3.2888x; 1.0400x over previous
//
#include <hip/hip_runtime.h>
#include <hip/hip_fp16.h>

#define N_ROWS 65536
#define D_COLS 1024
#define M_ROWS 32768
#define QROWS  16384   // rows per scatter workgroup (64KB f32 LDS, 2 blocks/CU)

using u32 = unsigned int;
using u16 = unsigned short;
typedef float f32x4 __attribute__((ext_vector_type(4)));   // native vecs for nontemporal
typedef int   i32x4 __attribute__((ext_vector_type(4)));

// ---- ws[0] = 0 (abs-max accumulator) ----
__global__ void init_ws_k(u32* ws) {
    if (threadIdx.x == 0 && blockIdx.x == 0) ws[0] = 0u;
}

// ---- 64x64-tile transpose: idx[M,D]->idxT[D,M] (u16), upd[M,D]*scl[j] -> updT[D,M] (fp16)
//      nt loads (single-use streams); normal stores (re-read by scatter, keep in L3). ----
__global__ __launch_bounds__(256) void t_idx_upd_k(const int* __restrict__ idx,
                                                   const float* __restrict__ upd,
                                                   const float* __restrict__ scl,
                                                   u16* __restrict__ idxT,
                                                   __half* __restrict__ updT) {
    __shared__ u32   sidx[64][65];
    __shared__ float supd[64][65];
    const int j0 = (int)(blockIdx.x & 15) * 64;   // 16 j-tiles
    const int i0 = (int)(blockIdx.x >> 4) * 64;   // 512 i-tiles
    const int t = threadIdx.x;

    {
        const int rr = t >> 2, c4 = t & 3;
        const int*   ip = idx + (size_t)(i0 + rr) * D_COLS + j0;
        const float* up = upd + (size_t)(i0 + rr) * D_COLS + j0;
        #pragma unroll
        for (int cq = 0; cq < 4; ++cq) {
            const int jc = cq * 16 + c4 * 4;
            const i32x4 iv = __builtin_nontemporal_load((const i32x4*)(ip + jc));
            const f32x4 uv = __builtin_nontemporal_load((const f32x4*)(up + jc));
            sidx[rr][jc] = (u32)iv.x; sidx[rr][jc+1] = (u32)iv.y;
            sidx[rr][jc+2] = (u32)iv.z; sidx[rr][jc+3] = (u32)iv.w;
            supd[rr][jc] = uv.x; supd[rr][jc+1] = uv.y;
            supd[rr][jc+2] = uv.z; supd[rr][jc+3] = uv.w;
        }
    }
    __syncthreads();

    {
        const int jj = t >> 2, seg = t & 3;
        const __half hs = __float2half(scl[j0 + jj]);   // exact fp16 scale
        u32 wi[8], wh[8];
        #pragma unroll
        for (int p = 0; p < 8; ++p) {
            const int r = seg * 16 + 2 * p;
            const u32 a = sidx[r][jj] & 0xffffu, b = sidx[r + 1][jj] & 0xffffu;
            wi[p] = a | (b << 16);
            const __half2 h2 = __halves2half2(__hmul(__float2half(supd[r][jj]), hs),
                                              __hmul(__float2half(supd[r + 1][jj]), hs));
            wh[p] = *reinterpret_cast<const u32*>(&h2);
        }
        u16* di = idxT + (size_t)(j0 + jj) * M_ROWS + i0 + seg * 16;
        __half* dh = updT + (size_t)(j0 + jj) * M_ROWS + i0 + seg * 16;
        ((uint4*)di)[0] = uint4{wi[0], wi[1], wi[2], wi[3]};
        ((uint4*)di)[1] = uint4{wi[4], wi[5], wi[6], wi[7]};
        ((uint4*)dh)[0] = uint4{wh[0], wh[1], wh[2], wh[3]};
        ((uint4*)dh)[1] = uint4{wh[4], wh[5], wh[6], wh[7]};
    }
}

// ---- per (column j, quarter h): zero 64KB LDS f32 acc, scan column's updates,
//      LDS-atomic accumulate own quarter, dense fp16 write to sumT[D][N].
//      XCD swizzle co-schedules the 4 quarters of each column on one XCD (L2 reuse). ----
__global__ __launch_bounds__(512) void scatter_q_k(const u16* __restrict__ idxT,
                                                   const __half* __restrict__ updT,
                                                   __half* __restrict__ sumT) {
    __shared__ float acc[QROWS];                  // 64 KB -> 2 blocks/CU
    const int bid = (blockIdx.x & 7) * 512 + (blockIdx.x >> 3);  // bijective, 4096%8==0
    const int j = bid >> 2;                       // column 0..1023
    const int h = bid & 3;                        // row quarter
    const int tid = threadIdx.x;

    float4* acc4 = (float4*)acc;
    for (int t = tid; t < QROWS / 4; t += 512) acc4[t] = float4{0.f, 0.f, 0.f, 0.f};

    const int4* ip4 = (const int4*)(idxT + (size_t)j * M_ROWS);  // 4096 int4
    const int4* up4 = (const int4*)(updT + (size_t)j * M_ROWS);
    __syncthreads();

    #pragma unroll
    for (int k = 0; k < 8; ++k) {
        const int t = k * 512 + tid;
        const int4 iv = ip4[t];
        const int4 uv = up4[t];
        const u32 iw[4] = {(u32)iv.x, (u32)iv.y, (u32)iv.z, (u32)iv.w};
        const u32 uw[4] = {(u32)uv.x, (u32)uv.y, (u32)uv.z, (u32)uv.w};
        #pragma unroll
        for (int e = 0; e < 4; ++e) {
            const int r0 = iw[e] & 0xffff, r1 = iw[e] >> 16;
            const __half2 h2 = *reinterpret_cast<const __half2*>(&uw[e]);
            if ((r0 >> 14) == h) atomicAdd(&acc[r0 & (QROWS - 1)], __half2float(__low2half(h2)));
            if ((r1 >> 14) == h) atomicAdd(&acc[r1 & (QROWS - 1)], __half2float(__high2half(h2)));
        }
    }
    __syncthreads();

    __half2* dst = (__half2*)(sumT + (size_t)j * N_ROWS + h * QROWS);
    for (int t = tid; t < QROWS / 2; t += 512)
        dst[t] = __floats2half2_rn(acc[2 * t], acc[2 * t + 1]);
}

// ---- 64x64 tiles: out = var*s + sumT^T; var via nt loads (single-use);
//      out via normal stores (quant re-reads from L3); fused abs-max. ----
__global__ __launch_bounds__(256) void finalize_k(const int* __restrict__ var,
                                                  const __half* __restrict__ sumT,
                                                  const float* __restrict__ var_scale,
                                                  float* __restrict__ outf,
                                                  u32* __restrict__ ws) {
    __shared__ float sm[64][65];
    __shared__ float wmax[4];
    const int r0 = (int)(blockIdx.x >> 4) * 64;   // 1024 row-tiles
    const int j0 = (int)(blockIdx.x & 15) * 64;   // 16 col-tiles
    const int tid = threadIdx.x;
    const float s = var_scale[0];

    {
        const int jj = tid >> 2, seg = tid & 3;
        const __half* colp = sumT + (size_t)(j0 + jj) * N_ROWS + r0 + seg * 16;
        #pragma unroll
        for (int q = 0; q < 2; ++q) {
            const uint4 w = ((const uint4*)colp)[q];
            const u32 wv[4] = {w.x, w.y, w.z, w.w};
            #pragma unroll
            for (int i = 0; i < 4; ++i) {
                const __half2 hh = *reinterpret_cast<const __half2*>(&wv[i]);
                const float2 f = __half22float2(hh);
                const int rr = seg * 16 + q * 8 + i * 2;
                sm[rr][jj] = f.x;
                sm[rr + 1][jj] = f.y;
            }
        }
    }
    __syncthreads();

    float m = 0.f;
    #pragma unroll
    for (int k = 0; k < 4; ++k) {
        const int l = k * 256 + tid;              // 0..1023 int4 units
        const int rr = l >> 4, c4 = l & 15;
        const i32x4 v = __builtin_nontemporal_load(
            (const i32x4*)(var + (size_t)(r0 + rr) * D_COLS + j0) + c4);
        float4 o;
        o.x = (float)v.x * s + sm[rr][c4 * 4 + 0];
        o.y = (float)v.y * s + sm[rr][c4 * 4 + 1];
        o.z = (float)v.z * s + sm[rr][c4 * 4 + 2];
        o.w = (float)v.w * s + sm[rr][c4 * 4 + 3];
        ((float4*)(outf + (size_t)(r0 + rr) * D_COLS + j0))[c4] = o;
        m = fmaxf(m, fmaxf(fmaxf(fabsf(o.x), fabsf(o.y)),
                           fmaxf(fabsf(o.z), fabsf(o.w))));
    }
    for (int off = 32; off; off >>= 1) m = fmaxf(m, __shfl_xor(m, off));
    if ((tid & 63) == 0) wmax[tid >> 6] = m;
    __syncthreads();
    if (tid == 0) {
        m = fmaxf(fmaxf(wmax[0], wmax[1]), fmaxf(wmax[2], wmax[3]));
        atomicMax(ws, __float_as_uint(m));
    }
}

// ---- y = clip(rint(out * 127/max), -128, 127) stored as f32; write scale ----
__global__ __launch_bounds__(256) void quant_k(const float4* __restrict__ outf4,
                                               f32x4* __restrict__ y4,
                                               const u32* __restrict__ ws,
                                               float* __restrict__ scale_out, int n4) {
    const float mx = __uint_as_float(ws[0]);
    const float inv = 127.0f / mx;
    int gid = blockIdx.x * 256 + threadIdx.x;
    if (gid == 0) scale_out[0] = mx / 127.0f;
    const int stride = gridDim.x * 256;
    for (int i = gid; i < n4; i += stride) {
        float4 v = outf4[i];                      // hot in L3 if thrash theory holds
        f32x4 o;
        o.x = fminf(fmaxf(rintf(v.x * inv), -128.f), 127.f);
        o.y = fminf(fmaxf(rintf(v.y * inv), -128.f), 127.f);
        o.z = fminf(fmaxf(rintf(v.z * inv), -128.f), 127.f);
        o.w = fminf(fmaxf(rintf(v.w * inv), -128.f), 127.f);
        __builtin_nontemporal_store(o, &y4[i]);   // y never re-read
    }
}

extern "C" void kernel_launch(void* const* d_in, const int* in_sizes, int n_in,
                              void* d_out, int out_size, void* d_ws, size_t ws_size,
                              hipStream_t stream) {
    const int*   var       = (const int*)d_in[0];     // int8 transported as int32
    const float* var_scale = (const float*)d_in[1];
    const int*   idx       = (const int*)d_in[2];
    const float* upd       = (const float*)d_in[3];   // fp16 transported as f32
    const float* scl       = (const float*)d_in[4];   // fp16 transported as f32

    float* y    = (float*)d_out;                      // y (f32) [N*D]
    float* outf = y + (size_t)N_ROWS * D_COLS;        // out (f32) [N*D]
    float* scale_out = y + 2 * (size_t)N_ROWS * D_COLS;

    // scratch packed into the (not-yet-written) y region: exactly 256 MB
    char* scratch = (char*)y;
    u16*    idxT = (u16*)scratch;                               // 64 MB
    __half* updT = (__half*)(scratch + (size_t)67108864);       // 64 MB
    __half* sumT = (__half*)(scratch + (size_t)134217728);      // 128 MB
    u32* ws = (u32*)d_ws;

    const int n4 = N_ROWS * D_COLS / 4;

    init_ws_k<<<1, 64, 0, stream>>>(ws);
    t_idx_upd_k<<<8192, 256, 0, stream>>>(idx, upd, scl, idxT, updT);
    scatter_q_k<<<4096, 512, 0, stream>>>(idxT, updT, sumT);
    finalize_k<<<16384, 256, 0, stream>>>(var, sumT, var_scale, outf, ws);
    quant_k<<<4096, 256, 0, stream>>>((const float4*)outf, (f32x4*)y, ws, scale_out, n4);
}